// Round 20
// baseline (146.542 us; speedup 1.0000x reference)
//
#include <hip/hip_runtime.h>
#include <hip/hip_bf16.h>
#include <stdint.h>

#define B_SZ 4
#define T_LEN 8192
#define D_DIM 512
#define M_TOT 32768
#define RB 64       // scan chunk rows == GEMM M-tile
#define NCH 128     // chunks per batch
#define SCS 260     // f32 LDS stride (256-col half-tile, r13-validated)

typedef __attribute__((ext_vector_type(8))) short bf16x8v;
typedef __attribute__((ext_vector_type(4))) float f32x4v;

__device__ __forceinline__ unsigned short f2bf(float f) {
  unsigned int u = __float_as_uint(f);
  u += 0x7fffu + ((u >> 16) & 1u);
  return (unsigned short)(u >> 16);
}
__device__ __forceinline__ float bf2f(unsigned short b) {
  return __uint_as_float(((unsigned int)b) << 16);
}
__device__ __forceinline__ float sigmoidf_(float x) { return 1.0f / (1.0f + expf(-x)); }

__device__ __forceinline__ bf16x8v pack8(float4 a, float4 b) {
  union { unsigned u[4]; bf16x8v v; } r;
  r.u[0] = (unsigned)f2bf(a.x) | ((unsigned)f2bf(a.y) << 16);
  r.u[1] = (unsigned)f2bf(a.z) | ((unsigned)f2bf(a.w) << 16);
  r.u[2] = (unsigned)f2bf(b.x) | ((unsigned)f2bf(b.y) << 16);
  r.u[3] = (unsigned)f2bf(b.z) | ((unsigned)f2bf(b.w) << 16);
  return r.v;
}

// ---------------------------------------------------------------------------
// Fragment-chunk layout (r13-validated): matrix [R][512] stored as chunks of
// 16 rows x 32 k; chunk id = rowblk*16 + kslice; lane l holds 8 bf16 at
// (row = rowblk*16 + (l&15), k = kslice*32 + (l>>4)*8). Fragment load =
// chunkbase + lane*16 : 1KB contiguous.
// prep: blocks 0..31 pack Wb, 32..63 pack Wc, block 64 packs papk.
__global__ void prep_k(const float* __restrict__ Wb, const float* __restrict__ Wc,
                       const float* __restrict__ A, unsigned short* __restrict__ wpk,
                       unsigned short* __restrict__ papk) {
  const int b = blockIdx.x;
  const int tid = threadIdx.x;
  if (b == 64) {
#pragma unroll
    for (int s = 0; s < 2; ++s) {
      int ch = s * 256 + tid;
      float a = sigmoidf_(A[ch]);
      float p = a;
      int lhi = ((ch >> 3) & 3) << 4;
      int e = ch & 7;
      int csl = ch >> 5;
      for (int row = 0; row < RB; ++row) {
        int chunk = (row >> 4) * 16 + csl;
        int lane = (row & 15) | lhi;
        papk[chunk * 512 + lane * 8 + e] = f2bf(p);
        p *= a;
      }
    }
    return;
  }
  __shared__ unsigned short sd[16 * 520];
  const float* src = (b < 32) ? Wb + (size_t)b * 8192 : Wc + (size_t)(b - 32) * 8192;
  unsigned short* dst =
      (b < 32) ? wpk + (size_t)b * 8192 : wpk + 262144 + (size_t)(b - 32) * 8192;
#pragma unroll
  for (int it = 0; it < 4; ++it) {
    int idx = (it * 256 + tid) * 8;
    int row = idx >> 9, col = idx & 511;
    float4 v0 = *(const float4*)&src[row * 512 + col];
    float4 v1 = *(const float4*)&src[row * 512 + col + 4];
    uint4 o;
    o.x = (unsigned)f2bf(v0.x) | ((unsigned)f2bf(v0.y) << 16);
    o.y = (unsigned)f2bf(v0.z) | ((unsigned)f2bf(v0.w) << 16);
    o.z = (unsigned)f2bf(v1.x) | ((unsigned)f2bf(v1.y) << 16);
    o.w = (unsigned)f2bf(v1.z) | ((unsigned)f2bf(v1.w) << 16);
    *(uint4*)&sd[row * 520 + col] = o;
  }
  __syncthreads();
#pragma unroll
  for (int it = 0; it < 4; ++it) {
    int idx = it * 256 + tid;
    int cs = idx >> 6, l = idx & 63;
    uint4 v = *(const uint4*)&sd[(l & 15) * 520 + cs * 32 + (l >> 4) * 8];
    *(uint4*)&dst[(size_t)cs * 512 + l * 8] = v;
  }
}

// ---------------------------------------------------------------------------
// In-place chunk-carry prefix (batched loads). grid=B_SZ, block=512.
__global__ void carry_k(const float* __restrict__ A, float* __restrict__ cst) {
  const int ch = threadIdx.x;
  const int bi = blockIdx.x;
  float a = sigmoidf_(A[ch]);
  float p = a;
#pragma unroll
  for (int i = 0; i < 6; ++i) p *= p;  // a^64
  float H = 0.f;
  for (int cg = 0; cg < 16; ++cg) {
    float v[8];
    size_t base = ((size_t)bi * NCH + cg * 8) * 512 + ch;
#pragma unroll
    for (int i = 0; i < 8; ++i) v[i] = cst[base + (size_t)i * 512];
#pragma unroll
    for (int i = 0; i < 8; ++i) {
      float lf = v[i];
      cst[base + (size_t)i * 512] = H;
      H = fmaf(p, H, lf);
    }
  }
}

// ---------------------------------------------------------------------------
// 64x256 bf16 GEMM per block, 512 threads = 8 waves (2M x 4N), wave tile
// 32x64, acc[2][4] = 32 AGPR (occupancy play: ~97 regs/wave -> 2 blocks/CU
// = 16 waves/CU, 2x the TLP of every prior fused round). Block (mt, nh)
// computes rows mt*64..+64, cols nh*256..+256. Grid = 1024.
// K-loop: no LDS/barriers; fragments direct from global.
// MODE 0: A = x f32 fragment-order + convert in reg (fused); epilogue =
//         fused 64-row scan over this block's 256 cols -> packed h + finals.
// MODE 1: A = packed h + papk*carry fix in reg (fused); epilogue = per-wave
//         LDS-transposed coalesced f32 C store.
template <int MODE>
__global__ __launch_bounds__(512, 4) void gemm_k(
    const void* __restrict__ Aptr, const unsigned short* __restrict__ Bpk,
    float* __restrict__ C, const float* __restrict__ Ad,
    unsigned short* __restrict__ hOut, float* __restrict__ cst,
    const unsigned short* __restrict__ papk) {
  __shared__ union {
    float sc[RB * SCS];    // MODE0 scan tile 64 x 260 (66.6 KB -> 2 blocks/CU)
    float tp[8][16 * 68];  // MODE1 per-wave transpose (34.8 KB)
  } sm;

  const int tid = threadIdx.x;
  const int lane = tid & 63;
  const int w = tid >> 6;       // 0..7
  const int wmi = w >> 2;       // M half (32 rows)
  const int wni = w & 3;        // N quarter (64 cols)
  const int flat = blockIdx.x;
  const int mt = flat >> 1;     // 64-row tile == scan chunk id (0..511)
  const int nh = flat & 1;      // 256-col half
  const int l15 = lane & 15;
  const int g4 = lane >> 4;

  // B rowblk base for this wave's 64 output cols: (nh*256 + wni*64)/16
  const unsigned short* bB = Bpk + ((size_t)(nh * 16 + wni * 4)) * 8192 + lane * 8;

  f32x4v acc[2][4] = {};

  if constexpr (MODE == 0) {
    const float* ax = (const float*)Aptr + (size_t)(mt * 64 + wmi * 32 + l15) * 512 + g4 * 8;
#pragma unroll 4
    for (int t = 0; t < 16; ++t) {
      bf16x8v af[2], bf_[4];
#pragma unroll
      for (int i = 0; i < 2; ++i) {
        float4 u0 = *(const float4*)&ax[(size_t)i * 8192 + t * 32];
        float4 u1 = *(const float4*)&ax[(size_t)i * 8192 + t * 32 + 4];
        af[i] = pack8(u0, u1);
      }
#pragma unroll
      for (int j = 0; j < 4; ++j)
        bf_[j] = *(const bf16x8v*)&bB[(size_t)j * 8192 + t * 512];
#pragma unroll
      for (int i = 0; i < 2; ++i)
#pragma unroll
        for (int j = 0; j < 4; ++j)
          acc[i][j] = __builtin_amdgcn_mfma_f32_16x16x32_bf16(af[i], bf_[j], acc[i][j], 0, 0, 0);
    }
  } else {
    const unsigned short* ah =
        (const unsigned short*)Aptr + ((size_t)(mt * 4 + wmi * 2) * 16) * 512 + lane * 8;
    const unsigned short* pa = papk + ((size_t)(wmi * 2) * 16) * 512 + lane * 8;
    const float* cg = cst + (size_t)mt * 512 + g4 * 8;
#pragma unroll 4
    for (int t = 0; t < 16; ++t) {
      float4 c0 = *(const float4*)&cg[t * 32];
      float4 c1 = *(const float4*)&cg[t * 32 + 4];
      float cf[8] = {c0.x, c0.y, c0.z, c0.w, c1.x, c1.y, c1.z, c1.w};
      bf16x8v af[2], bf_[4];
#pragma unroll
      for (int i = 0; i < 2; ++i) {
        uint4 hv = *(const uint4*)&ah[(size_t)i * 8192 + t * 512];
        uint4 pv = *(const uint4*)&pa[(size_t)i * 8192 + t * 512];
        const unsigned* hw = (const unsigned*)&hv;
        const unsigned* pw = (const unsigned*)&pv;
        union { unsigned u[4]; bf16x8v v; } r;
#pragma unroll
        for (int q = 0; q < 4; ++q) {
          float o0 = fmaf(bf2f((unsigned short)(pw[q] & 0xffff)), cf[2 * q],
                          bf2f((unsigned short)(hw[q] & 0xffff)));
          float o1 = fmaf(bf2f((unsigned short)(pw[q] >> 16)), cf[2 * q + 1],
                          bf2f((unsigned short)(hw[q] >> 16)));
          r.u[q] = (unsigned)f2bf(o0) | ((unsigned)f2bf(o1) << 16);
        }
        af[i] = r.v;
      }
#pragma unroll
      for (int j = 0; j < 4; ++j)
        bf_[j] = *(const bf16x8v*)&bB[(size_t)j * 8192 + t * 512];
#pragma unroll
      for (int i = 0; i < 2; ++i)
#pragma unroll
        for (int j = 0; j < 4; ++j)
          acc[i][j] = __builtin_amdgcn_mfma_f32_16x16x32_bf16(af[i], bf_[j], acc[i][j], 0, 0, 0);
    }
  }

  if constexpr (MODE == 0) {
    // fused 64-row chunk scan over this block's 256 cols (single tile)
    __syncthreads();  // K-loop had no barriers; ensure union reuse is safe
#pragma unroll
    for (int i = 0; i < 2; ++i)
#pragma unroll
      for (int j = 0; j < 4; ++j)
#pragma unroll
        for (int r = 0; r < 4; ++r)
          sm.sc[(wmi * 32 + i * 16 + g4 * 4 + r) * SCS + wni * 64 + j * 16 + l15] = acc[i][j][r];
    __syncthreads();
    if (tid < 256) {
      float a2 = sigmoidf_(Ad[nh * 256 + tid]);
      float h = 0.f;
#pragma unroll 8
      for (int tt = 0; tt < RB; ++tt) {
        h = fmaf(a2, h, sm.sc[tt * SCS + tid]);
        sm.sc[tt * SCS + tid] = h;
      }
      cst[(size_t)mt * 512 + nh * 256 + tid] = h;  // chunk-local final (half)
    }
    __syncthreads();
    // write this half's h PACKED (kslices nh*8 + cs, cs<8; rowblks rbl<4)
#pragma unroll
    for (int p = 0; p < 4; ++p) {
      int idx = p * 512 + tid;
      int cl = idx >> 6, l = idx & 63;
      int rbl = cl >> 3, cs = cl & 7;
      const float* s = &sm.sc[(rbl * 16 + (l & 15)) * SCS + cs * 32 + (l >> 4) * 8];
      unsigned w0 = (unsigned)f2bf(s[0]) | ((unsigned)f2bf(s[1]) << 16);
      unsigned w1 = (unsigned)f2bf(s[2]) | ((unsigned)f2bf(s[3]) << 16);
      unsigned w2 = (unsigned)f2bf(s[4]) | ((unsigned)f2bf(s[5]) << 16);
      unsigned w3 = (unsigned)f2bf(s[6]) | ((unsigned)f2bf(s[7]) << 16);
      *(uint4*)&hOut[(((size_t)mt * 4 + rbl) * 16 + nh * 8 + cs) * 512 + l * 8] =
          make_uint4(w0, w1, w2, w3);
    }
  } else {
    // coalesced C store via per-wave LDS transpose (own 16x68 region)
    __syncthreads();
    float* tp = sm.tp[w];
#pragma unroll
    for (int i = 0; i < 2; ++i) {
#pragma unroll
      for (int j = 0; j < 4; ++j)
#pragma unroll
        for (int r = 0; r < 4; ++r)
          tp[(g4 * 4 + r) * 68 + j * 16 + l15] = acc[i][j][r];
#pragma unroll
      for (int p = 0; p < 4; ++p) {
        f32x4v v = *(const f32x4v*)&tp[(p * 4 + g4) * 68 + l15 * 4];
        *(f32x4v*)&C[(size_t)(mt * 64 + wmi * 32 + i * 16 + p * 4 + g4) * 512 + nh * 256 +
                     wni * 64 + l15 * 4] = v;
      }
    }
  }
}

// ---------------------------------------------------------------------------
extern "C" void kernel_launch(void* const* d_in, const int* in_sizes, int n_in,
                              void* d_out, int out_size, void* d_ws, size_t ws_size,
                              hipStream_t stream) {
  const float* x = (const float*)d_in[0];
  const float* W_B = (const float*)d_in[1];
  const float* W_C = (const float*)d_in[2];
  const float* A = (const float*)d_in[3];
  float* out = (float*)d_out;
  char* ws = (char*)d_ws;

  // ws: [0,1M) Wpk (Wb|Wc packed) | [1M,+64K) papk bf16 | [1.125M,2.125M)
  //     cst[512][512] f32 | [2.125M, +32M) h packed bf16
  unsigned short* Wpk = (unsigned short*)ws;
  unsigned short* papk = (unsigned short*)(ws + 0x100000);
  float* cst = (float*)(ws + 0x120000);
  unsigned short* hpk = (unsigned short*)(ws + 0x220000);

  prep_k<<<65, 256, 0, stream>>>(W_B, W_C, A, Wpk, papk);

  gemm_k<0><<<1024, 512, 0, stream>>>(x, Wpk, nullptr, A, hpk, cst, nullptr);
  carry_k<<<B_SZ, 512, 0, stream>>>(A, cst);
  gemm_k<1><<<1024, 512, 0, stream>>>(hpk, Wpk + 262144, out, nullptr, nullptr, cst, papk);
}

// Round 21
// 146.064 us; speedup vs baseline: 1.0033x; 1.0033x over previous
//
#include <hip/hip_runtime.h>
#include <hip/hip_bf16.h>
#include <stdint.h>

#define B_SZ 4
#define T_LEN 8192
#define D_DIM 512
#define M_TOT 32768
#define RB 64       // scan chunk rows
#define NCH 128     // chunks per batch
#define SCX 132     // f32 LDS stride for the 256x128 scan tile

typedef __attribute__((ext_vector_type(8))) short bf16x8v;
typedef __attribute__((ext_vector_type(4))) float f32x4v;

__device__ __forceinline__ unsigned short f2bf(float f) {
  unsigned int u = __float_as_uint(f);
  u += 0x7fffu + ((u >> 16) & 1u);
  return (unsigned short)(u >> 16);
}
__device__ __forceinline__ float bf2f(unsigned short b) {
  return __uint_as_float(((unsigned int)b) << 16);
}
__device__ __forceinline__ float sigmoidf_(float x) { return 1.0f / (1.0f + expf(-x)); }

__device__ __forceinline__ bf16x8v pack8(float4 a, float4 b) {
  union { unsigned u[4]; bf16x8v v; } r;
  r.u[0] = (unsigned)f2bf(a.x) | ((unsigned)f2bf(a.y) << 16);
  r.u[1] = (unsigned)f2bf(a.z) | ((unsigned)f2bf(a.w) << 16);
  r.u[2] = (unsigned)f2bf(b.x) | ((unsigned)f2bf(b.y) << 16);
  r.u[3] = (unsigned)f2bf(b.z) | ((unsigned)f2bf(b.w) << 16);
  return r.v;
}

// ---------------------------------------------------------------------------
// Fragment-chunk layout (r13-validated): matrix [R][512] stored as chunks of
// 16 rows x 32 k; chunk id = rowblk*16 + kslice; lane l holds 8 bf16 at
// (row = rowblk*16 + (l&15), k = kslice*32 + (l>>4)*8). Fragment load =
// chunkbase + lane*16 : 1KB contiguous. Packed layout is rowblk-major, so a
// 128-col weight panel (8 rowblks) is one contiguous 128KB range.
// prep: blocks 0..31 pack Wb, 32..63 pack Wc, block 64 packs papk.
__global__ void prep_k(const float* __restrict__ Wb, const float* __restrict__ Wc,
                       const float* __restrict__ A, unsigned short* __restrict__ wpk,
                       unsigned short* __restrict__ papk) {
  const int b = blockIdx.x;
  const int tid = threadIdx.x;
  if (b == 64) {
#pragma unroll
    for (int s = 0; s < 2; ++s) {
      int ch = s * 256 + tid;
      float a = sigmoidf_(A[ch]);
      float p = a;
      int lhi = ((ch >> 3) & 3) << 4;
      int e = ch & 7;
      int csl = ch >> 5;
      for (int row = 0; row < RB; ++row) {
        int chunk = (row >> 4) * 16 + csl;
        int lane = (row & 15) | lhi;
        papk[chunk * 512 + lane * 8 + e] = f2bf(p);
        p *= a;
      }
    }
    return;
  }
  __shared__ unsigned short sd[16 * 520];
  const float* src = (b < 32) ? Wb + (size_t)b * 8192 : Wc + (size_t)(b - 32) * 8192;
  unsigned short* dst =
      (b < 32) ? wpk + (size_t)b * 8192 : wpk + 262144 + (size_t)(b - 32) * 8192;
#pragma unroll
  for (int it = 0; it < 4; ++it) {
    int idx = (it * 256 + tid) * 8;
    int row = idx >> 9, col = idx & 511;
    float4 v0 = *(const float4*)&src[row * 512 + col];
    float4 v1 = *(const float4*)&src[row * 512 + col + 4];
    uint4 o;
    o.x = (unsigned)f2bf(v0.x) | ((unsigned)f2bf(v0.y) << 16);
    o.y = (unsigned)f2bf(v0.z) | ((unsigned)f2bf(v0.w) << 16);
    o.z = (unsigned)f2bf(v1.x) | ((unsigned)f2bf(v1.y) << 16);
    o.w = (unsigned)f2bf(v1.z) | ((unsigned)f2bf(v1.w) << 16);
    *(uint4*)&sd[row * 520 + col] = o;
  }
  __syncthreads();
#pragma unroll
  for (int it = 0; it < 4; ++it) {
    int idx = it * 256 + tid;
    int cs = idx >> 6, l = idx & 63;
    uint4 v = *(const uint4*)&sd[(l & 15) * 520 + cs * 32 + (l >> 4) * 8];
    *(uint4*)&dst[(size_t)cs * 512 + l * 8] = v;
  }
}

// ---------------------------------------------------------------------------
// In-place chunk-carry prefix (batched loads). grid=B_SZ, block=512.
__global__ void carry_k(const float* __restrict__ A, float* __restrict__ cst) {
  const int ch = threadIdx.x;
  const int bi = blockIdx.x;
  float a = sigmoidf_(A[ch]);
  float p = a;
#pragma unroll
  for (int i = 0; i < 6; ++i) p *= p;  // a^64
  float H = 0.f;
  for (int cg = 0; cg < 16; ++cg) {
    float v[8];
    size_t base = ((size_t)bi * NCH + cg * 8) * 512 + ch;
#pragma unroll
    for (int i = 0; i < 8; ++i) v[i] = cst[base + (size_t)i * 512];
#pragma unroll
    for (int i = 0; i < 8; ++i) {
      float lf = v[i];
      cst[base + (size_t)i * 512] = H;
      H = fmaf(p, H, lf);
    }
  }
}

// ---------------------------------------------------------------------------
// 256x128 bf16 GEMM per block: WEIGHT-STATIONARY B IN LDS. The block's whole
// 128-col weight panel (128KB packed bf16) is staged into LDS once; K-loop
// reads B via conflict-free ds_read_b128 (base+lane*16) with NO barriers.
// 8 waves = 4M x 2N, wave 64x64, acc[4][4]. Grid = 512 (128 rowtiles x 4
// coltiles), XCD-swizzled so the 4 coltiles of a rowtile share one XCD's L2
// (A re-reads served by L2, r5-validated mechanism).
// MODE 0: A = x f32 fragment-order + convert in reg; epilogue = single-pass
//         4-chunk scan (all 512 threads) -> packed h + chunk finals.
// MODE 1: A = packed h + papk*carry fix in reg; epilogue = per-wave
//         LDS-transposed coalesced f32 C store.
template <int MODE>
__global__ __launch_bounds__(512, 1) void gemm_k(
    const void* __restrict__ Aptr, const unsigned short* __restrict__ Bpk,
    float* __restrict__ C, const float* __restrict__ Ad,
    unsigned short* __restrict__ hOut, float* __restrict__ cst,
    const unsigned short* __restrict__ papk) {
  __shared__ union {
    unsigned short bst[65536];  // B panel: 8 rowblks x 16 ks x 512 (128 KB)
    float sc[256 * SCX];        // scan tile 256 x 132 (135.2 KB)
    float tp[8][16 * 68];       // MODE1 per-wave transpose (34.8 KB)
  } sm;

  const int tid = threadIdx.x;
  const int lane = tid & 63;
  const int w = tid >> 6;   // 0..7
  const int wmi = w >> 1;   // M quarter (64 rows = one scan chunk)
  const int wni = w & 1;    // N half (64 cols)
  const int l15 = lane & 15;
  const int g4 = lane >> 4;

  // XCD swizzle: 512 blocks = 8 XCDs x 64 works; work = rowtile*4 + coltile
  const int flat = blockIdx.x;
  const int work = ((flat & 7) << 6) | (flat >> 3);
  const int rt = work >> 2;    // row tile (256 rows)
  const int nb = work & 3;     // 128-col panel
  const int bm = rt * 256;

  // ---- stage B panel (contiguous 128KB of packed weights) into LDS ----
  {
    const unsigned short* bsrc = Bpk + (size_t)nb * 65536;
#pragma unroll
    for (int it = 0; it < 16; ++it) {
      int idx = it * 512 + tid;
      *(uint4*)&sm.bst[idx * 8] = *(const uint4*)&bsrc[(size_t)idx * 8];
    }
  }
  __syncthreads();  // one-time; K-loop below is barrier-free

  f32x4v acc[4][4] = {};

  if constexpr (MODE == 0) {
    const float* ax = (const float*)Aptr + (size_t)(bm + wmi * 64 + l15) * 512 + g4 * 8;
#pragma unroll 4
    for (int t = 0; t < 16; ++t) {
      bf16x8v af[4], bf_[4];
#pragma unroll
      for (int i = 0; i < 4; ++i) {
        float4 u0 = *(const float4*)&ax[(size_t)i * 8192 + t * 32];
        float4 u1 = *(const float4*)&ax[(size_t)i * 8192 + t * 32 + 4];
        af[i] = pack8(u0, u1);
      }
#pragma unroll
      for (int j = 0; j < 4; ++j)
        bf_[j] = *(const bf16x8v*)&sm.bst[((wni * 4 + j) * 16 + t) * 512 + lane * 8];
#pragma unroll
      for (int i = 0; i < 4; ++i)
#pragma unroll
        for (int j = 0; j < 4; ++j)
          acc[i][j] = __builtin_amdgcn_mfma_f32_16x16x32_bf16(af[i], bf_[j], acc[i][j], 0, 0, 0);
    }
  } else {
    const int g = bm / 64 + wmi;  // this wave's scan chunk
    const unsigned short* ah =
        (const unsigned short*)Aptr + ((size_t)(bm / 16 + wmi * 4) * 16) * 512 + lane * 8;
    const unsigned short* pa = papk + lane * 8;
    const float* cg = cst + (size_t)g * 512 + g4 * 8;
#pragma unroll 4
    for (int t = 0; t < 16; ++t) {
      float4 c0 = *(const float4*)&cg[t * 32];
      float4 c1 = *(const float4*)&cg[t * 32 + 4];
      float cf[8] = {c0.x, c0.y, c0.z, c0.w, c1.x, c1.y, c1.z, c1.w};
      bf16x8v af[4], bf_[4];
#pragma unroll
      for (int i = 0; i < 4; ++i) {
        uint4 hv = *(const uint4*)&ah[((size_t)i * 16 + t) * 512];
        uint4 pv = *(const uint4*)&pa[((size_t)i * 16 + t) * 512];
        const unsigned* hw = (const unsigned*)&hv;
        const unsigned* pw = (const unsigned*)&pv;
        union { unsigned u[4]; bf16x8v v; } r;
#pragma unroll
        for (int q = 0; q < 4; ++q) {
          float o0 = fmaf(bf2f((unsigned short)(pw[q] & 0xffff)), cf[2 * q],
                          bf2f((unsigned short)(hw[q] & 0xffff)));
          float o1 = fmaf(bf2f((unsigned short)(pw[q] >> 16)), cf[2 * q + 1],
                          bf2f((unsigned short)(hw[q] >> 16)));
          r.u[q] = (unsigned)f2bf(o0) | ((unsigned)f2bf(o1) << 16);
        }
        af[i] = r.v;
      }
#pragma unroll
      for (int j = 0; j < 4; ++j)
        bf_[j] = *(const bf16x8v*)&sm.bst[((wni * 4 + j) * 16 + t) * 512 + lane * 8];
#pragma unroll
      for (int i = 0; i < 4; ++i)
#pragma unroll
        for (int j = 0; j < 4; ++j)
          acc[i][j] = __builtin_amdgcn_mfma_f32_16x16x32_bf16(af[i], bf_[j], acc[i][j], 0, 0, 0);
    }
  }

  __syncthreads();  // B panel dead; union space reused by epilogues

  if constexpr (MODE == 0) {
    // scatter ALL 4 chunks' acc (256 rows x 128 cols) into sc
#pragma unroll
    for (int i = 0; i < 4; ++i)
#pragma unroll
      for (int j = 0; j < 4; ++j)
#pragma unroll
        for (int r = 0; r < 4; ++r)
          sm.sc[(wmi * 64 + i * 16 + g4 * 4 + r) * SCX + wni * 64 + j * 16 + l15] = acc[i][j][r];
    __syncthreads();
    // single-pass scan: thread = (chunk q = tid>>7, col c = tid&127)
    {
      const int q = tid >> 7, c = tid & 127;
      float a2 = sigmoidf_(Ad[nb * 128 + c]);
      float h = 0.f;
#pragma unroll 8
      for (int tt = 0; tt < RB; ++tt) {
        int idx = (q * 64 + tt) * SCX + c;
        h = fmaf(a2, h, sm.sc[idx]);
        sm.sc[idx] = h;
      }
      cst[(size_t)(bm / 64 + q) * 512 + nb * 128 + c] = h;  // chunk-local final
    }
    __syncthreads();
    // packed h write: 64 frag-chunks (q<4 x rbl<4 x cs<4), 8 uint4/thread
#pragma unroll
    for (int p = 0; p < 8; ++p) {
      int idx = p * 512 + tid;
      int u = idx >> 6, l = idx & 63;
      int q = u >> 4, rbl = (u >> 2) & 3, cs = u & 3;
      const float* s = &sm.sc[(q * 64 + rbl * 16 + (l & 15)) * SCX + cs * 32 + (l >> 4) * 8];
      unsigned w0 = (unsigned)f2bf(s[0]) | ((unsigned)f2bf(s[1]) << 16);
      unsigned w1 = (unsigned)f2bf(s[2]) | ((unsigned)f2bf(s[3]) << 16);
      unsigned w2 = (unsigned)f2bf(s[4]) | ((unsigned)f2bf(s[5]) << 16);
      unsigned w3 = (unsigned)f2bf(s[6]) | ((unsigned)f2bf(s[7]) << 16);
      int chunk = (bm / 16 + q * 4 + rbl) * 16 + nb * 4 + cs;
      *(uint4*)&hOut[(size_t)chunk * 512 + l * 8] = make_uint4(w0, w1, w2, w3);
    }
  } else {
    // coalesced C store via per-wave LDS transpose (own 16x68 region)
    float* tp = sm.tp[w];
#pragma unroll
    for (int i = 0; i < 4; ++i) {
#pragma unroll
      for (int j = 0; j < 4; ++j)
#pragma unroll
        for (int r = 0; r < 4; ++r)
          tp[(g4 * 4 + r) * 68 + j * 16 + l15] = acc[i][j][r];
#pragma unroll
      for (int p = 0; p < 4; ++p) {
        f32x4v v = *(const f32x4v*)&tp[(p * 4 + g4) * 68 + l15 * 4];
        *(f32x4v*)&C[(size_t)(bm + wmi * 64 + i * 16 + p * 4 + g4) * 512 + nb * 128 +
                     wni * 64 + l15 * 4] = v;
      }
    }
  }
}

// ---------------------------------------------------------------------------
extern "C" void kernel_launch(void* const* d_in, const int* in_sizes, int n_in,
                              void* d_out, int out_size, void* d_ws, size_t ws_size,
                              hipStream_t stream) {
  const float* x = (const float*)d_in[0];
  const float* W_B = (const float*)d_in[1];
  const float* W_C = (const float*)d_in[2];
  const float* A = (const float*)d_in[3];
  float* out = (float*)d_out;
  char* ws = (char*)d_ws;

  // ws: [0,1M) Wpk (Wb|Wc packed) | [1M,+64K) papk bf16 | [1.125M,2.125M)
  //     cst[512][512] f32 | [2.125M, +32M) h packed bf16
  unsigned short* Wpk = (unsigned short*)ws;
  unsigned short* papk = (unsigned short*)(ws + 0x100000);
  float* cst = (float*)(ws + 0x120000);
  unsigned short* hpk = (unsigned short*)(ws + 0x220000);

  prep_k<<<65, 256, 0, stream>>>(W_B, W_C, A, Wpk, papk);

  gemm_k<0><<<512, 512, 0, stream>>>(x, Wpk, nullptr, A, hpk, cst, nullptr);
  carry_k<<<B_SZ, 512, 0, stream>>>(A, cst);
  gemm_k<1><<<512, 512, 0, stream>>>(hpk, Wpk + 262144, out, nullptr, nullptr, cst, papk);
}

// Round 22
// 114.773 us; speedup vs baseline: 1.2768x; 1.2726x over previous
//
#include <hip/hip_runtime.h>
#include <hip/hip_bf16.h>
#include <stdint.h>

#define B_SZ 4
#define T_LEN 8192
#define D_DIM 512
#define M_TOT 32768
#define RB 64       // scan chunk rows == GEMM M-tile
#define NCH 128     // chunks per batch
#define SCS 132     // f32 LDS stride (128-col pass tile)

typedef __attribute__((ext_vector_type(8))) short bf16x8v;
typedef __attribute__((ext_vector_type(4))) float f32x4v;

__device__ __forceinline__ unsigned short f2bf(float f) {
  unsigned int u = __float_as_uint(f);
  u += 0x7fffu + ((u >> 16) & 1u);
  return (unsigned short)(u >> 16);
}
__device__ __forceinline__ float bf2f(unsigned short b) {
  return __uint_as_float(((unsigned int)b) << 16);
}
__device__ __forceinline__ float sigmoidf_(float x) { return 1.0f / (1.0f + expf(-x)); }

__device__ __forceinline__ bf16x8v pack8(float4 a, float4 b) {
  union { unsigned u[4]; bf16x8v v; } r;
  r.u[0] = (unsigned)f2bf(a.x) | ((unsigned)f2bf(a.y) << 16);
  r.u[1] = (unsigned)f2bf(a.z) | ((unsigned)f2bf(a.w) << 16);
  r.u[2] = (unsigned)f2bf(b.x) | ((unsigned)f2bf(b.y) << 16);
  r.u[3] = (unsigned)f2bf(b.z) | ((unsigned)f2bf(b.w) << 16);
  return r.v;
}

// ---------------------------------------------------------------------------
// Fragment-chunk layout (r13-validated): matrix [R][512] stored as chunks of
// 16 rows x 32 k; chunk id = rowblk*16 + kslice; lane l holds 8 bf16 at
// (row = rowblk*16 + (l&15), k = kslice*32 + (l>>4)*8). Fragment load =
// chunkbase + lane*16 : 1KB contiguous.
// prep: blocks 0..31 pack Wb, 32..63 pack Wc, block 64 packs papk.
__global__ void prep_k(const float* __restrict__ Wb, const float* __restrict__ Wc,
                       const float* __restrict__ A, unsigned short* __restrict__ wpk,
                       unsigned short* __restrict__ papk) {
  const int b = blockIdx.x;
  const int tid = threadIdx.x;
  if (b == 64) {
#pragma unroll
    for (int s = 0; s < 2; ++s) {
      int ch = s * 256 + tid;
      float a = sigmoidf_(A[ch]);
      float p = a;
      int lhi = ((ch >> 3) & 3) << 4;
      int e = ch & 7;
      int csl = ch >> 5;
      for (int row = 0; row < RB; ++row) {
        int chunk = (row >> 4) * 16 + csl;
        int lane = (row & 15) | lhi;
        papk[chunk * 512 + lane * 8 + e] = f2bf(p);
        p *= a;
      }
    }
    return;
  }
  __shared__ unsigned short sd[16 * 520];
  const float* src = (b < 32) ? Wb + (size_t)b * 8192 : Wc + (size_t)(b - 32) * 8192;
  unsigned short* dst =
      (b < 32) ? wpk + (size_t)b * 8192 : wpk + 262144 + (size_t)(b - 32) * 8192;
#pragma unroll
  for (int it = 0; it < 4; ++it) {
    int idx = (it * 256 + tid) * 8;
    int row = idx >> 9, col = idx & 511;
    float4 v0 = *(const float4*)&src[row * 512 + col];
    float4 v1 = *(const float4*)&src[row * 512 + col + 4];
    uint4 o;
    o.x = (unsigned)f2bf(v0.x) | ((unsigned)f2bf(v0.y) << 16);
    o.y = (unsigned)f2bf(v0.z) | ((unsigned)f2bf(v0.w) << 16);
    o.z = (unsigned)f2bf(v1.x) | ((unsigned)f2bf(v1.y) << 16);
    o.w = (unsigned)f2bf(v1.z) | ((unsigned)f2bf(v1.w) << 16);
    *(uint4*)&sd[row * 520 + col] = o;
  }
  __syncthreads();
#pragma unroll
  for (int it = 0; it < 4; ++it) {
    int idx = it * 256 + tid;
    int cs = idx >> 6, l = idx & 63;
    uint4 v = *(const uint4*)&sd[(l & 15) * 520 + cs * 32 + (l >> 4) * 8];
    *(uint4*)&dst[(size_t)cs * 512 + l * 8] = v;
  }
}

// ---------------------------------------------------------------------------
// In-place chunk-carry prefix (batched loads). grid=B_SZ, block=512.
__global__ void carry_k(const float* __restrict__ A, float* __restrict__ cst) {
  const int ch = threadIdx.x;
  const int bi = blockIdx.x;
  float a = sigmoidf_(A[ch]);
  float p = a;
#pragma unroll
  for (int i = 0; i < 6; ++i) p *= p;  // a^64
  float H = 0.f;
  for (int cg = 0; cg < 16; ++cg) {
    float v[8];
    size_t base = ((size_t)bi * NCH + cg * 8) * 512 + ch;
#pragma unroll
    for (int i = 0; i < 8; ++i) v[i] = cst[base + (size_t)i * 512];
#pragma unroll
    for (int i = 0; i < 8; ++i) {
      float lf = v[i];
      cst[base + (size_t)i * 512] = H;
      H = fmaf(p, H, lf);
    }
  }
}

// ---------------------------------------------------------------------------
// 64x256 bf16 GEMM per block, 256 threads = 4 waves (2M x 2N), wave tile
// 32x128 (r16's — best measured), acc[2][8]. 3 blocks/CU = 12 waves/CU
// (+50% TLP vs r16's 8). Grid = 1024 = 512 mt x 2 nh, XCD-swizzled so both
// col-halves of an mt share one XCD's L2 (A re-read becomes an L2 hit).
// K-loop: no LDS/barriers; fragments direct from global.
// MODE 0: A = x f32 fragment-order + convert in reg (fused); epilogue =
//         fused 64-row scan over this block's 256 cols in two 128-col passes.
// MODE 1: A = packed h + papk*carry fix in reg (fused); epilogue = per-wave
//         LDS-transposed coalesced f32 C store.
template <int MODE>
__global__ __launch_bounds__(256, 3) void gemm_k(
    const void* __restrict__ Aptr, const unsigned short* __restrict__ Bpk,
    float* __restrict__ C, const float* __restrict__ Ad,
    unsigned short* __restrict__ hOut, float* __restrict__ cst,
    const unsigned short* __restrict__ papk) {
  __shared__ union {
    float sc[RB * SCS];    // MODE0 scan pass tile 64 x 132 (33.8 KB)
    float tp[4][16 * 132]; // MODE1 per-wave transpose (33.8 KB)
  } sm;

  const int tid = threadIdx.x;
  const int lane = tid & 63;
  const int w = tid >> 6;   // 0..3
  const int wmi = w >> 1;   // M half (32 rows)
  const int wni = w & 1;    // N half (128 cols within block's 256)
  const int l15 = lane & 15;
  const int g4 = lane >> 4;

  // XCD swizzle: 1024 blocks = 8 XCDs x 128 works; work = mt*2 + nh
  const int flat = blockIdx.x;
  const int work = ((flat & 7) << 7) | (flat >> 3);
  const int mt = work >> 1;   // 64-row tile == scan chunk id (0..511)
  const int nh = work & 1;    // 256-col half

  // wave's 128 output cols start at nh*256 + wni*128 -> rowblk nh*16+wni*8
  const unsigned short* bB = Bpk + (size_t)(nh * 16 + wni * 8) * 8192 + lane * 8;

  f32x4v acc[2][8] = {};

  if constexpr (MODE == 0) {
    const float* ax = (const float*)Aptr + (size_t)(mt * 64 + wmi * 32 + l15) * 512 + g4 * 8;
#pragma unroll 4
    for (int t = 0; t < 16; ++t) {
      bf16x8v af[2], bf_[8];
#pragma unroll
      for (int i = 0; i < 2; ++i) {
        float4 u0 = *(const float4*)&ax[(size_t)i * 8192 + t * 32];
        float4 u1 = *(const float4*)&ax[(size_t)i * 8192 + t * 32 + 4];
        af[i] = pack8(u0, u1);
      }
#pragma unroll
      for (int j = 0; j < 8; ++j)
        bf_[j] = *(const bf16x8v*)&bB[(size_t)j * 8192 + t * 512];
#pragma unroll
      for (int i = 0; i < 2; ++i)
#pragma unroll
        for (int j = 0; j < 8; ++j)
          acc[i][j] = __builtin_amdgcn_mfma_f32_16x16x32_bf16(af[i], bf_[j], acc[i][j], 0, 0, 0);
    }
  } else {
    const unsigned short* ah =
        (const unsigned short*)Aptr + ((size_t)(mt * 4 + wmi * 2) * 16) * 512 + lane * 8;
    const unsigned short* pa = papk + ((size_t)(wmi * 2) * 16) * 512 + lane * 8;
    const float* cg = cst + (size_t)mt * 512 + g4 * 8;
#pragma unroll 4
    for (int t = 0; t < 16; ++t) {
      float4 c0 = *(const float4*)&cg[t * 32];
      float4 c1 = *(const float4*)&cg[t * 32 + 4];
      float cf[8] = {c0.x, c0.y, c0.z, c0.w, c1.x, c1.y, c1.z, c1.w};
      bf16x8v af[2], bf_[8];
#pragma unroll
      for (int i = 0; i < 2; ++i) {
        uint4 hv = *(const uint4*)&ah[(size_t)i * 8192 + t * 512];
        uint4 pv = *(const uint4*)&pa[(size_t)i * 8192 + t * 512];
        const unsigned* hw = (const unsigned*)&hv;
        const unsigned* pw = (const unsigned*)&pv;
        union { unsigned u[4]; bf16x8v v; } r;
#pragma unroll
        for (int q = 0; q < 4; ++q) {
          float o0 = fmaf(bf2f((unsigned short)(pw[q] & 0xffff)), cf[2 * q],
                          bf2f((unsigned short)(hw[q] & 0xffff)));
          float o1 = fmaf(bf2f((unsigned short)(pw[q] >> 16)), cf[2 * q + 1],
                          bf2f((unsigned short)(hw[q] >> 16)));
          r.u[q] = (unsigned)f2bf(o0) | ((unsigned)f2bf(o1) << 16);
        }
        af[i] = r.v;
      }
#pragma unroll
      for (int j = 0; j < 8; ++j)
        bf_[j] = *(const bf16x8v*)&bB[(size_t)j * 8192 + t * 512];
#pragma unroll
      for (int i = 0; i < 2; ++i)
#pragma unroll
        for (int j = 0; j < 8; ++j)
          acc[i][j] = __builtin_amdgcn_mfma_f32_16x16x32_bf16(af[i], bf_[j], acc[i][j], 0, 0, 0);
    }
  }

  if constexpr (MODE == 0) {
    // fused 64-row chunk scan over this block's 256 cols, two 128-col passes
#pragma unroll
    for (int ps = 0; ps < 2; ++ps) {
      if (wni == ps) {  // waves owning these 128 cols scatter acc (D-layout)
#pragma unroll
        for (int i = 0; i < 2; ++i)
#pragma unroll
          for (int j = 0; j < 8; ++j)
#pragma unroll
            for (int r = 0; r < 4; ++r)
              sm.sc[(wmi * 32 + i * 16 + g4 * 4 + r) * SCS + j * 16 + l15] = acc[i][j][r];
      }
      __syncthreads();
      if (tid < 128) {
        float a2 = sigmoidf_(Ad[nh * 256 + ps * 128 + tid]);
        float h = 0.f;
#pragma unroll 8
        for (int tt = 0; tt < RB; ++tt) {
          h = fmaf(a2, h, sm.sc[tt * SCS + tid]);
          sm.sc[tt * SCS + tid] = h;
        }
        cst[(size_t)mt * 512 + nh * 256 + ps * 128 + tid] = h;  // chunk final
      }
      __syncthreads();
      // write this pass's h PACKED: kslices nh*8+ps*4+cs (cs<4), rbl<4
#pragma unroll
      for (int p = 0; p < 4; ++p) {
        int idx = p * 256 + tid;
        int cl = idx >> 6, l = idx & 63;
        int rbl = cl >> 2, cs = cl & 3;
        const float* s = &sm.sc[(rbl * 16 + (l & 15)) * SCS + cs * 32 + (l >> 4) * 8];
        unsigned w0 = (unsigned)f2bf(s[0]) | ((unsigned)f2bf(s[1]) << 16);
        unsigned w1 = (unsigned)f2bf(s[2]) | ((unsigned)f2bf(s[3]) << 16);
        unsigned w2 = (unsigned)f2bf(s[4]) | ((unsigned)f2bf(s[5]) << 16);
        unsigned w3 = (unsigned)f2bf(s[6]) | ((unsigned)f2bf(s[7]) << 16);
        *(uint4*)&hOut[(((size_t)mt * 4 + rbl) * 16 + nh * 8 + ps * 4 + cs) * 512 + l * 8] =
            make_uint4(w0, w1, w2, w3);
      }
      __syncthreads();
    }
  } else {
    // coalesced C store via per-wave LDS transpose (own 16x132 region)
    float* tp = sm.tp[w];
#pragma unroll
    for (int i = 0; i < 2; ++i) {
#pragma unroll
      for (int j = 0; j < 8; ++j)
#pragma unroll
        for (int r = 0; r < 4; ++r)
          tp[(g4 * 4 + r) * 132 + j * 16 + l15] = acc[i][j][r];
#pragma unroll
      for (int p = 0; p < 8; ++p) {
        int row = p * 2 + (lane >> 5);
        int slot = lane & 31;
        f32x4v v = *(const f32x4v*)&tp[row * 132 + slot * 4];
        *(f32x4v*)&C[(size_t)(mt * 64 + wmi * 32 + i * 16 + row) * 512 + nh * 256 +
                     wni * 128 + slot * 4] = v;
      }
    }
  }
}

// ---------------------------------------------------------------------------
extern "C" void kernel_launch(void* const* d_in, const int* in_sizes, int n_in,
                              void* d_out, int out_size, void* d_ws, size_t ws_size,
                              hipStream_t stream) {
  const float* x = (const float*)d_in[0];
  const float* W_B = (const float*)d_in[1];
  const float* W_C = (const float*)d_in[2];
  const float* A = (const float*)d_in[3];
  float* out = (float*)d_out;
  char* ws = (char*)d_ws;

  // ws: [0,1M) Wpk (Wb|Wc packed) | [1M,+64K) papk bf16 | [1.125M,2.125M)
  //     cst[512][512] f32 | [2.125M, +32M) h packed bf16
  unsigned short* Wpk = (unsigned short*)ws;
  unsigned short* papk = (unsigned short*)(ws + 0x100000);
  float* cst = (float*)(ws + 0x120000);
  unsigned short* hpk = (unsigned short*)(ws + 0x220000);

  prep_k<<<65, 256, 0, stream>>>(W_B, W_C, A, Wpk, papk);

  gemm_k<0><<<1024, 256, 0, stream>>>(x, Wpk, nullptr, A, hpk, cst, nullptr);
  carry_k<<<B_SZ, 512, 0, stream>>>(A, cst);
  gemm_k<1><<<1024, 256, 0, stream>>>(hpk, Wpk + 262144, out, nullptr, nullptr, cst, papk);
}

// Round 23
// 96.823 us; speedup vs baseline: 1.5135x; 1.1854x over previous
//
#include <hip/hip_runtime.h>
#include <hip/hip_bf16.h>
#include <stdint.h>

#define B_SZ 4
#define T_LEN 8192
#define D_DIM 512
#define M_TOT 32768
#define RB 64       // scan chunk rows
#define NCH 128     // chunks per batch
#define SCS 516     // f32 LDS stride for the full 512-col scan tile

typedef __attribute__((ext_vector_type(8))) short bf16x8v;
typedef __attribute__((ext_vector_type(4))) float f32x4v;

__device__ __forceinline__ unsigned short f2bf(float f) {
  unsigned int u = __float_as_uint(f);
  u += 0x7fffu + ((u >> 16) & 1u);
  return (unsigned short)(u >> 16);
}
__device__ __forceinline__ float bf2f(unsigned short b) {
  return __uint_as_float(((unsigned int)b) << 16);
}
__device__ __forceinline__ float sigmoidf_(float x) { return 1.0f / (1.0f + expf(-x)); }

__device__ __forceinline__ bf16x8v pack8(float4 a, float4 b) {
  union { unsigned u[4]; bf16x8v v; } r;
  r.u[0] = (unsigned)f2bf(a.x) | ((unsigned)f2bf(a.y) << 16);
  r.u[1] = (unsigned)f2bf(a.z) | ((unsigned)f2bf(a.w) << 16);
  r.u[2] = (unsigned)f2bf(b.x) | ((unsigned)f2bf(b.y) << 16);
  r.u[3] = (unsigned)f2bf(b.z) | ((unsigned)f2bf(b.w) << 16);
  return r.v;
}

// ---------------------------------------------------------------------------
// Fragment-chunk layout (r13-validated): matrix [R][512] stored as chunks of
// 16 rows x 32 k; chunk id = rowblk*16 + kslice; lane l holds 8 bf16 at
// (row = rowblk*16 + (l&15), k = kslice*32 + (l>>4)*8). Fragment load =
// chunkbase + lane*16 : 1KB contiguous.
// prep: blocks 0..31 pack Wb, 32..63 pack Wc, block 64 packs papk.
__global__ void prep_k(const float* __restrict__ Wb, const float* __restrict__ Wc,
                       const float* __restrict__ A, unsigned short* __restrict__ wpk,
                       unsigned short* __restrict__ papk) {
  const int b = blockIdx.x;
  const int tid = threadIdx.x;
  if (b == 64) {
#pragma unroll
    for (int s = 0; s < 2; ++s) {
      int ch = s * 256 + tid;
      float a = sigmoidf_(A[ch]);
      float p = a;
      int lhi = ((ch >> 3) & 3) << 4;
      int e = ch & 7;
      int csl = ch >> 5;
      for (int row = 0; row < RB; ++row) {
        int chunk = (row >> 4) * 16 + csl;
        int lane = (row & 15) | lhi;
        papk[chunk * 512 + lane * 8 + e] = f2bf(p);
        p *= a;
      }
    }
    return;
  }
  __shared__ unsigned short sd[16 * 520];
  const float* src = (b < 32) ? Wb + (size_t)b * 8192 : Wc + (size_t)(b - 32) * 8192;
  unsigned short* dst =
      (b < 32) ? wpk + (size_t)b * 8192 : wpk + 262144 + (size_t)(b - 32) * 8192;
#pragma unroll
  for (int it = 0; it < 4; ++it) {
    int idx = (it * 256 + tid) * 8;
    int row = idx >> 9, col = idx & 511;
    float4 v0 = *(const float4*)&src[row * 512 + col];
    float4 v1 = *(const float4*)&src[row * 512 + col + 4];
    uint4 o;
    o.x = (unsigned)f2bf(v0.x) | ((unsigned)f2bf(v0.y) << 16);
    o.y = (unsigned)f2bf(v0.z) | ((unsigned)f2bf(v0.w) << 16);
    o.z = (unsigned)f2bf(v1.x) | ((unsigned)f2bf(v1.y) << 16);
    o.w = (unsigned)f2bf(v1.z) | ((unsigned)f2bf(v1.w) << 16);
    *(uint4*)&sd[row * 520 + col] = o;
  }
  __syncthreads();
#pragma unroll
  for (int it = 0; it < 4; ++it) {
    int idx = it * 256 + tid;
    int cs = idx >> 6, l = idx & 63;
    uint4 v = *(const uint4*)&sd[(l & 15) * 520 + cs * 32 + (l >> 4) * 8];
    *(uint4*)&dst[(size_t)cs * 512 + l * 8] = v;
  }
}

// ---------------------------------------------------------------------------
// In-place chunk-carry prefix (batched loads). grid=B_SZ, block=512.
__global__ void carry_k(const float* __restrict__ A, float* __restrict__ cst) {
  const int ch = threadIdx.x;
  const int bi = blockIdx.x;
  float a = sigmoidf_(A[ch]);
  float p = a;
#pragma unroll
  for (int i = 0; i < 6; ++i) p *= p;  // a^64
  float H = 0.f;
  for (int cg = 0; cg < 16; ++cg) {
    float v[8];
    size_t base = ((size_t)bi * NCH + cg * 8) * 512 + ch;
#pragma unroll
    for (int i = 0; i < 8; ++i) v[i] = cst[base + (size_t)i * 512];
#pragma unroll
    for (int i = 0; i < 8; ++i) {
      float lf = v[i];
      cst[base + (size_t)i * 512] = H;
      H = fmaf(p, H, lf);
    }
  }
}

// ---------------------------------------------------------------------------
// 128x512 bf16 GEMM per block (r16 exactly — session best), 512 threads =
// 8 waves (2M x 4N), wave tile 64x128, acc[4][8]. K-loop: no LDS/barriers;
// fragments direct from global. Grid = 256. + T5 s_setprio around MFMA.
// MODE 0: A = x f32 fragment-order + convert in reg (fused); epilogue = two
//         fused 64-row chunk scans over the full 512-col tile.
// MODE 1: A = packed h + papk*carry fix in reg (fused); epilogue = per-wave
//         LDS-transposed coalesced f32 C store.
template <int MODE>
__global__ __launch_bounds__(512, 2) void gemm_k(
    const void* __restrict__ Aptr, const unsigned short* __restrict__ Bpk,
    float* __restrict__ C, const float* __restrict__ Ad,
    unsigned short* __restrict__ hOut, float* __restrict__ cst,
    const unsigned short* __restrict__ papk) {
  __shared__ union {
    float sc[RB * SCS];     // MODE0 scan tile 64 x 516 (132 KB)
    float tp[8][16 * 132];  // MODE1 per-wave transpose (67.6 KB)
  } sm;

  const int tid = threadIdx.x;
  const int lane = tid & 63;
  const int w = tid >> 6;   // 0..7
  const int wmi = w >> 2;   // M half (64 rows = one scan chunk)
  const int wni = w & 3;    // N quarter (128 cols)
  const int mt = blockIdx.x;
  const int l15 = lane & 15;
  const int g4 = lane >> 4;

  const unsigned short* bB = Bpk + ((size_t)(wni * 8) * 16) * 512 + lane * 8;

  f32x4v acc[4][8] = {};

  if constexpr (MODE == 0) {
    const float* ax = (const float*)Aptr + (size_t)(mt * 128 + wmi * 64 + l15) * 512 + g4 * 8;
#pragma unroll 2
    for (int t = 0; t < 16; ++t) {
      bf16x8v af[4], bf_[8];
#pragma unroll
      for (int i = 0; i < 4; ++i) {
        float4 u0 = *(const float4*)&ax[(size_t)i * 8192 + t * 32];
        float4 u1 = *(const float4*)&ax[(size_t)i * 8192 + t * 32 + 4];
        af[i] = pack8(u0, u1);
      }
#pragma unroll
      for (int j = 0; j < 8; ++j)
        bf_[j] = *(const bf16x8v*)&bB[(size_t)j * 8192 + t * 512];
      __builtin_amdgcn_s_setprio(1);
#pragma unroll
      for (int i = 0; i < 4; ++i)
#pragma unroll
        for (int j = 0; j < 8; ++j)
          acc[i][j] = __builtin_amdgcn_mfma_f32_16x16x32_bf16(af[i], bf_[j], acc[i][j], 0, 0, 0);
      __builtin_amdgcn_s_setprio(0);
    }
  } else {
    const unsigned short* ah =
        (const unsigned short*)Aptr + ((size_t)(mt * 8 + wmi * 4) * 16) * 512 + lane * 8;
    const unsigned short* pa = papk + lane * 8;
    const float* cg = cst + (size_t)(mt * 2 + wmi) * 512 + g4 * 8;
#pragma unroll 2
    for (int t = 0; t < 16; ++t) {
      float4 c0 = *(const float4*)&cg[t * 32];
      float4 c1 = *(const float4*)&cg[t * 32 + 4];
      float cf[8] = {c0.x, c0.y, c0.z, c0.w, c1.x, c1.y, c1.z, c1.w};
      bf16x8v af[4], bf_[8];
#pragma unroll
      for (int i = 0; i < 4; ++i) {
        uint4 hv = *(const uint4*)&ah[(size_t)i * 8192 + t * 512];
        uint4 pv = *(const uint4*)&pa[(size_t)i * 8192 + t * 512];
        const unsigned* hw = (const unsigned*)&hv;
        const unsigned* pw = (const unsigned*)&pv;
        union { unsigned u[4]; bf16x8v v; } r;
#pragma unroll
        for (int q = 0; q < 4; ++q) {
          float o0 = fmaf(bf2f((unsigned short)(pw[q] & 0xffff)), cf[2 * q],
                          bf2f((unsigned short)(hw[q] & 0xffff)));
          float o1 = fmaf(bf2f((unsigned short)(pw[q] >> 16)), cf[2 * q + 1],
                          bf2f((unsigned short)(hw[q] >> 16)));
          r.u[q] = (unsigned)f2bf(o0) | ((unsigned)f2bf(o1) << 16);
        }
        af[i] = r.v;
      }
#pragma unroll
      for (int j = 0; j < 8; ++j)
        bf_[j] = *(const bf16x8v*)&bB[(size_t)j * 8192 + t * 512];
      __builtin_amdgcn_s_setprio(1);
#pragma unroll
      for (int i = 0; i < 4; ++i)
#pragma unroll
        for (int j = 0; j < 8; ++j)
          acc[i][j] = __builtin_amdgcn_mfma_f32_16x16x32_bf16(af[i], bf_[j], acc[i][j], 0, 0, 0);
      __builtin_amdgcn_s_setprio(0);
    }
  }

  if constexpr (MODE == 0) {
    // two fused 64-row chunk scans over the full 512-col tile
    float a2 = 0.f;
    if (tid < 512) a2 = sigmoidf_(Ad[tid]);
#pragma unroll
    for (int c = 0; c < 2; ++c) {
      if (wmi == c) {  // waves owning these 64 rows scatter acc (D-layout)
#pragma unroll
        for (int i = 0; i < 4; ++i)
#pragma unroll
          for (int j = 0; j < 8; ++j)
#pragma unroll
            for (int r = 0; r < 4; ++r)
              sm.sc[(i * 16 + g4 * 4 + r) * SCS + wni * 128 + j * 16 + l15] = acc[i][j][r];
      }
      __syncthreads();
      {
        float h = 0.f;
#pragma unroll 8
        for (int tt = 0; tt < RB; ++tt) {
          h = fmaf(a2, h, sm.sc[tt * SCS + tid]);
          sm.sc[tt * SCS + tid] = h;
        }
        cst[(size_t)(mt * 2 + c) * 512 + tid] = h;  // chunk-local final
      }
      __syncthreads();
      // write chunk's h PACKED: 4096 uint4, 8 per thread
#pragma unroll
      for (int p = 0; p < 8; ++p) {
        int idx = p * 512 + tid;
        int cl = idx >> 6, l = idx & 63;
        int rbl = cl >> 4, cs = cl & 15;
        const float* s = &sm.sc[(rbl * 16 + (l & 15)) * SCS + cs * 32 + (l >> 4) * 8];
        unsigned w0 = (unsigned)f2bf(s[0]) | ((unsigned)f2bf(s[1]) << 16);
        unsigned w1 = (unsigned)f2bf(s[2]) | ((unsigned)f2bf(s[3]) << 16);
        unsigned w2 = (unsigned)f2bf(s[4]) | ((unsigned)f2bf(s[5]) << 16);
        unsigned w3 = (unsigned)f2bf(s[6]) | ((unsigned)f2bf(s[7]) << 16);
        *(uint4*)&hOut[(((size_t)(mt * 2 + c) * 4 + rbl) * 16 + cs) * 512 + l * 8] =
            make_uint4(w0, w1, w2, w3);
      }
      __syncthreads();
    }
  } else {
    // coalesced C store via per-wave LDS transpose (own 16x132 region)
    float* tp = sm.tp[w];
#pragma unroll
    for (int i = 0; i < 4; ++i) {
#pragma unroll
      for (int j = 0; j < 8; ++j)
#pragma unroll
        for (int r = 0; r < 4; ++r)
          tp[(g4 * 4 + r) * 132 + j * 16 + l15] = acc[i][j][r];
#pragma unroll
      for (int p = 0; p < 8; ++p) {
        int row = p * 2 + (lane >> 5);
        int slot = lane & 31;
        f32x4v v = *(const f32x4v*)&tp[row * 132 + slot * 4];
        *(f32x4v*)&C[(size_t)(mt * 128 + wmi * 64 + i * 16 + row) * 512 + wni * 128 + slot * 4] =
            v;
      }
    }
  }
}

// ---------------------------------------------------------------------------
extern "C" void kernel_launch(void* const* d_in, const int* in_sizes, int n_in,
                              void* d_out, int out_size, void* d_ws, size_t ws_size,
                              hipStream_t stream) {
  const float* x = (const float*)d_in[0];
  const float* W_B = (const float*)d_in[1];
  const float* W_C = (const float*)d_in[2];
  const float* A = (const float*)d_in[3];
  float* out = (float*)d_out;
  char* ws = (char*)d_ws;

  // ws: [0,1M) Wpk (Wb|Wc packed) | [1M,+64K) papk bf16 | [1.125M,2.125M)
  //     cst[512][512] f32 | [2.125M, +32M) h packed bf16
  unsigned short* Wpk = (unsigned short*)ws;
  unsigned short* papk = (unsigned short*)(ws + 0x100000);
  float* cst = (float*)(ws + 0x120000);
  unsigned short* hpk = (unsigned short*)(ws + 0x220000);

  prep_k<<<65, 256, 0, stream>>>(W_B, W_C, A, Wpk, papk);

  gemm_k<0><<<256, 512, 0, stream>>>(x, Wpk, nullptr, A, hpk, cst, nullptr);
  carry_k<<<B_SZ, 512, 0, stream>>>(A, cst);
  gemm_k<1><<<256, 512, 0, stream>>>(hpk, Wpk + 262144, out, nullptr, nullptr, cst, papk);
}

// Round 24
// 96.232 us; speedup vs baseline: 1.5228x; 1.0062x over previous
//
#include <hip/hip_runtime.h>
#include <hip/hip_bf16.h>
#include <stdint.h>

#define B_SZ 4
#define T_LEN 8192
#define D_DIM 512
#define M_TOT 32768
#define RB 64       // scan chunk rows
#define NCH 128     // chunks per batch
#define SCS 516     // f32 LDS stride for the full 512-col scan tile

typedef __attribute__((ext_vector_type(8))) short bf16x8v;
typedef __attribute__((ext_vector_type(4))) float f32x4v;

__device__ __forceinline__ unsigned short f2bf(float f) {
  unsigned int u = __float_as_uint(f);
  u += 0x7fffu + ((u >> 16) & 1u);
  return (unsigned short)(u >> 16);
}
__device__ __forceinline__ float bf2f(unsigned short b) {
  return __uint_as_float(((unsigned int)b) << 16);
}
__device__ __forceinline__ float sigmoidf_(float x) { return 1.0f / (1.0f + expf(-x)); }

__device__ __forceinline__ bf16x8v pack8(float4 a, float4 b) {
  union { unsigned u[4]; bf16x8v v; } r;
  r.u[0] = (unsigned)f2bf(a.x) | ((unsigned)f2bf(a.y) << 16);
  r.u[1] = (unsigned)f2bf(a.z) | ((unsigned)f2bf(a.w) << 16);
  r.u[2] = (unsigned)f2bf(b.x) | ((unsigned)f2bf(b.y) << 16);
  r.u[3] = (unsigned)f2bf(b.z) | ((unsigned)f2bf(b.w) << 16);
  return r.v;
}

// ---------------------------------------------------------------------------
// Fragment-chunk layout (r13-validated): matrix [R][512] stored as chunks of
// 16 rows x 32 k; chunk id = rowblk*16 + kslice; lane l holds 8 bf16 at
// (row = rowblk*16 + (l&15), k = kslice*32 + (l>>4)*8). Fragment load =
// chunkbase + lane*16 : 1KB contiguous.
// prep: blocks 0..31 pack Wb, 32..63 pack Wc, block 64 packs papk.
__global__ void prep_k(const float* __restrict__ Wb, const float* __restrict__ Wc,
                       const float* __restrict__ A, unsigned short* __restrict__ wpk,
                       unsigned short* __restrict__ papk) {
  const int b = blockIdx.x;
  const int tid = threadIdx.x;
  if (b == 64) {
#pragma unroll
    for (int s = 0; s < 2; ++s) {
      int ch = s * 256 + tid;
      float a = sigmoidf_(A[ch]);
      float p = a;
      int lhi = ((ch >> 3) & 3) << 4;
      int e = ch & 7;
      int csl = ch >> 5;
      for (int row = 0; row < RB; ++row) {
        int chunk = (row >> 4) * 16 + csl;
        int lane = (row & 15) | lhi;
        papk[chunk * 512 + lane * 8 + e] = f2bf(p);
        p *= a;
      }
    }
    return;
  }
  __shared__ unsigned short sd[16 * 520];
  const float* src = (b < 32) ? Wb + (size_t)b * 8192 : Wc + (size_t)(b - 32) * 8192;
  unsigned short* dst =
      (b < 32) ? wpk + (size_t)b * 8192 : wpk + 262144 + (size_t)(b - 32) * 8192;
#pragma unroll
  for (int it = 0; it < 4; ++it) {
    int idx = (it * 256 + tid) * 8;
    int row = idx >> 9, col = idx & 511;
    float4 v0 = *(const float4*)&src[row * 512 + col];
    float4 v1 = *(const float4*)&src[row * 512 + col + 4];
    uint4 o;
    o.x = (unsigned)f2bf(v0.x) | ((unsigned)f2bf(v0.y) << 16);
    o.y = (unsigned)f2bf(v0.z) | ((unsigned)f2bf(v0.w) << 16);
    o.z = (unsigned)f2bf(v1.x) | ((unsigned)f2bf(v1.y) << 16);
    o.w = (unsigned)f2bf(v1.z) | ((unsigned)f2bf(v1.w) << 16);
    *(uint4*)&sd[row * 520 + col] = o;
  }
  __syncthreads();
#pragma unroll
  for (int it = 0; it < 4; ++it) {
    int idx = it * 256 + tid;
    int cs = idx >> 6, l = idx & 63;
    uint4 v = *(const uint4*)&sd[(l & 15) * 520 + cs * 32 + (l >> 4) * 8];
    *(uint4*)&dst[(size_t)cs * 512 + l * 8] = v;
  }
}

// ---------------------------------------------------------------------------
// In-place chunk-carry prefix (batched loads). grid=B_SZ, block=512.
__global__ void carry_k(const float* __restrict__ A, float* __restrict__ cst) {
  const int ch = threadIdx.x;
  const int bi = blockIdx.x;
  float a = sigmoidf_(A[ch]);
  float p = a;
#pragma unroll
  for (int i = 0; i < 6; ++i) p *= p;  // a^64
  float H = 0.f;
  for (int cg = 0; cg < 16; ++cg) {
    float v[8];
    size_t base = ((size_t)bi * NCH + cg * 8) * 512 + ch;
#pragma unroll
    for (int i = 0; i < 8; ++i) v[i] = cst[base + (size_t)i * 512];
#pragma unroll
    for (int i = 0; i < 8; ++i) {
      float lf = v[i];
      cst[base + (size_t)i * 512] = H;
      H = fmaf(p, H, lf);
    }
  }
}

// ---------------------------------------------------------------------------
// 128x512 bf16 GEMM per block (r23 = r16 + T5 setprio, session best), 512
// threads = 8 waves (2M x 4N), wave tile 64x128, acc[4][8]. K-loop: no
// LDS/barriers; fragments direct from global; unroll 4 (more independent
// loads per scheduler window). Grid = 256.
// MODE 0: A = x f32 fragment-order + convert in reg (fused); epilogue = two
//         fused 64-row chunk scans over the full 512-col tile.
// MODE 1: A = packed h + papk*carry fix in reg (fused); epilogue = per-wave
//         LDS-transposed coalesced f32 C store.
template <int MODE>
__global__ __launch_bounds__(512, 2) void gemm_k(
    const void* __restrict__ Aptr, const unsigned short* __restrict__ Bpk,
    float* __restrict__ C, const float* __restrict__ Ad,
    unsigned short* __restrict__ hOut, float* __restrict__ cst,
    const unsigned short* __restrict__ papk) {
  __shared__ union {
    float sc[RB * SCS];     // MODE0 scan tile 64 x 516 (132 KB)
    float tp[8][16 * 132];  // MODE1 per-wave transpose (67.6 KB)
  } sm;

  const int tid = threadIdx.x;
  const int lane = tid & 63;
  const int w = tid >> 6;   // 0..7
  const int wmi = w >> 2;   // M half (64 rows = one scan chunk)
  const int wni = w & 3;    // N quarter (128 cols)
  const int mt = blockIdx.x;
  const int l15 = lane & 15;
  const int g4 = lane >> 4;

  const unsigned short* bB = Bpk + ((size_t)(wni * 8) * 16) * 512 + lane * 8;

  f32x4v acc[4][8] = {};

  if constexpr (MODE == 0) {
    const float* ax = (const float*)Aptr + (size_t)(mt * 128 + wmi * 64 + l15) * 512 + g4 * 8;
#pragma unroll 4
    for (int t = 0; t < 16; ++t) {
      bf16x8v af[4], bf_[8];
#pragma unroll
      for (int i = 0; i < 4; ++i) {
        float4 u0 = *(const float4*)&ax[(size_t)i * 8192 + t * 32];
        float4 u1 = *(const float4*)&ax[(size_t)i * 8192 + t * 32 + 4];
        af[i] = pack8(u0, u1);
      }
#pragma unroll
      for (int j = 0; j < 8; ++j)
        bf_[j] = *(const bf16x8v*)&bB[(size_t)j * 8192 + t * 512];
      __builtin_amdgcn_s_setprio(1);
#pragma unroll
      for (int i = 0; i < 4; ++i)
#pragma unroll
        for (int j = 0; j < 8; ++j)
          acc[i][j] = __builtin_amdgcn_mfma_f32_16x16x32_bf16(af[i], bf_[j], acc[i][j], 0, 0, 0);
      __builtin_amdgcn_s_setprio(0);
    }
  } else {
    const unsigned short* ah =
        (const unsigned short*)Aptr + ((size_t)(mt * 8 + wmi * 4) * 16) * 512 + lane * 8;
    const unsigned short* pa = papk + lane * 8;
    const float* cg = cst + (size_t)(mt * 2 + wmi) * 512 + g4 * 8;
#pragma unroll 4
    for (int t = 0; t < 16; ++t) {
      float4 c0 = *(const float4*)&cg[t * 32];
      float4 c1 = *(const float4*)&cg[t * 32 + 4];
      float cf[8] = {c0.x, c0.y, c0.z, c0.w, c1.x, c1.y, c1.z, c1.w};
      bf16x8v af[4], bf_[8];
#pragma unroll
      for (int i = 0; i < 4; ++i) {
        uint4 hv = *(const uint4*)&ah[(size_t)i * 8192 + t * 512];
        uint4 pv = *(const uint4*)&pa[(size_t)i * 8192 + t * 512];
        const unsigned* hw = (const unsigned*)&hv;
        const unsigned* pw = (const unsigned*)&pv;
        union { unsigned u[4]; bf16x8v v; } r;
#pragma unroll
        for (int q = 0; q < 4; ++q) {
          float o0 = fmaf(bf2f((unsigned short)(pw[q] & 0xffff)), cf[2 * q],
                          bf2f((unsigned short)(hw[q] & 0xffff)));
          float o1 = fmaf(bf2f((unsigned short)(pw[q] >> 16)), cf[2 * q + 1],
                          bf2f((unsigned short)(hw[q] >> 16)));
          r.u[q] = (unsigned)f2bf(o0) | ((unsigned)f2bf(o1) << 16);
        }
        af[i] = r.v;
      }
#pragma unroll
      for (int j = 0; j < 8; ++j)
        bf_[j] = *(const bf16x8v*)&bB[(size_t)j * 8192 + t * 512];
      __builtin_amdgcn_s_setprio(1);
#pragma unroll
      for (int i = 0; i < 4; ++i)
#pragma unroll
        for (int j = 0; j < 8; ++j)
          acc[i][j] = __builtin_amdgcn_mfma_f32_16x16x32_bf16(af[i], bf_[j], acc[i][j], 0, 0, 0);
      __builtin_amdgcn_s_setprio(0);
    }
  }

  if constexpr (MODE == 0) {
    // two fused 64-row chunk scans over the full 512-col tile
    float a2 = sigmoidf_(Ad[tid]);
#pragma unroll
    for (int c = 0; c < 2; ++c) {
      if (wmi == c) {  // waves owning these 64 rows scatter acc (D-layout)
#pragma unroll
        for (int i = 0; i < 4; ++i)
#pragma unroll
          for (int j = 0; j < 8; ++j)
#pragma unroll
            for (int r = 0; r < 4; ++r)
              sm.sc[(i * 16 + g4 * 4 + r) * SCS + wni * 128 + j * 16 + l15] = acc[i][j][r];
      }
      __syncthreads();
      {
        float h = 0.f;
#pragma unroll 8
        for (int tt = 0; tt < RB; ++tt) {
          h = fmaf(a2, h, sm.sc[tt * SCS + tid]);
          sm.sc[tt * SCS + tid] = h;
        }
        cst[(size_t)(mt * 2 + c) * 512 + tid] = h;  // chunk-local final
      }
      __syncthreads();
      // write chunk's h PACKED: 4096 uint4, 8 per thread
#pragma unroll
      for (int p = 0; p < 8; ++p) {
        int idx = p * 512 + tid;
        int cl = idx >> 6, l = idx & 63;
        int rbl = cl >> 4, cs = cl & 15;
        const float* s = &sm.sc[(rbl * 16 + (l & 15)) * SCS + cs * 32 + (l >> 4) * 8];
        unsigned w0 = (unsigned)f2bf(s[0]) | ((unsigned)f2bf(s[1]) << 16);
        unsigned w1 = (unsigned)f2bf(s[2]) | ((unsigned)f2bf(s[3]) << 16);
        unsigned w2 = (unsigned)f2bf(s[4]) | ((unsigned)f2bf(s[5]) << 16);
        unsigned w3 = (unsigned)f2bf(s[6]) | ((unsigned)f2bf(s[7]) << 16);
        *(uint4*)&hOut[(((size_t)(mt * 2 + c) * 4 + rbl) * 16 + cs) * 512 + l * 8] =
            make_uint4(w0, w1, w2, w3);
      }
      __syncthreads();
    }
  } else {
    // coalesced C store via per-wave LDS transpose (own 16x132 region)
    float* tp = sm.tp[w];
#pragma unroll
    for (int i = 0; i < 4; ++i) {
#pragma unroll
      for (int j = 0; j < 8; ++j)
#pragma unroll
        for (int r = 0; r < 4; ++r)
          tp[(g4 * 4 + r) * 132 + j * 16 + l15] = acc[i][j][r];
#pragma unroll
      for (int p = 0; p < 8; ++p) {
        int row = p * 2 + (lane >> 5);
        int slot = lane & 31;
        f32x4v v = *(const f32x4v*)&tp[row * 132 + slot * 4];
        *(f32x4v*)&C[(size_t)(mt * 128 + wmi * 64 + i * 16 + row) * 512 + wni * 128 + slot * 4] =
            v;
      }
    }
  }
}

// ---------------------------------------------------------------------------
extern "C" void kernel_launch(void* const* d_in, const int* in_sizes, int n_in,
                              void* d_out, int out_size, void* d_ws, size_t ws_size,
                              hipStream_t stream) {
  const float* x = (const float*)d_in[0];
  const float* W_B = (const float*)d_in[1];
  const float* W_C = (const float*)d_in[2];
  const float* A = (const float*)d_in[3];
  float* out = (float*)d_out;
  char* ws = (char*)d_ws;

  // ws: [0,1M) Wpk (Wb|Wc packed) | [1M,+64K) papk bf16 | [1.125M,2.125M)
  //     cst[512][512] f32 | [2.125M, +32M) h packed bf16
  unsigned short* Wpk = (unsigned short*)ws;
  unsigned short* papk = (unsigned short*)(ws + 0x100000);
  float* cst = (float*)(ws + 0x120000);
  unsigned short* hpk = (unsigned short*)(ws + 0x220000);

  prep_k<<<65, 256, 0, stream>>>(W_B, W_C, A, Wpk, papk);

  gemm_k<0><<<256, 512, 0, stream>>>(x, Wpk, nullptr, A, hpk, cst, nullptr);
  carry_k<<<B_SZ, 512, 0, stream>>>(A, cst);
  gemm_k<1><<<256, 512, 0, stream>>>(hpk, Wpk + 262144, out, nullptr, nullptr, cst, papk);
}